// Round 5
// baseline (223.272 us; speedup 1.0000x reference)
//
#include <hip/hip_runtime.h>
#include <hip/hip_bf16.h>

#define B_   128
#define T_   512
#define H_   512
#define V_   16
#define OUT_ 64
#define DH_  1024

// LDS: tab float4[V][H] (128K) + tsA float2[T] (4K) + vpk uchar[T] (512B)
#define TAB_BYTES (V_*H_*16)
#define TSA_BYTES (T_*8)
#define VPK_BYTES (T_)
#define SCAN_LDS  (TAB_BYTES + TSA_BYTES + VPK_BYTES)   // 135,680 B

__device__ __forceinline__ float bf2f(unsigned short u) {
    union { unsigned int i; float f; } x; x.i = ((unsigned int)u) << 16; return x.f;
}

// wave64 sum via DPP (VALU pipe only — no ds_bpermute). Result valid in lane 63.
__device__ __forceinline__ float wave_sum_dpp(float x) {
    int v;
    v = __builtin_amdgcn_update_dpp(0, __float_as_int(x), 0x111, 0xf, 0xf, true); // row_shr:1
    x += __int_as_float(v);
    v = __builtin_amdgcn_update_dpp(0, __float_as_int(x), 0x112, 0xf, 0xf, true); // row_shr:2
    x += __int_as_float(v);
    v = __builtin_amdgcn_update_dpp(0, __float_as_int(x), 0x114, 0xf, 0xf, true); // row_shr:4
    x += __int_as_float(v);
    v = __builtin_amdgcn_update_dpp(0, __float_as_int(x), 0x118, 0xf, 0xf, true); // row_shr:8
    x += __int_as_float(v);
    v = __builtin_amdgcn_update_dpp(0, __float_as_int(x), 0x142, 0xa, 0xf, true); // row_bcast:15 rows1,3
    x += __int_as_float(v);
    v = __builtin_amdgcn_update_dpp(0, __float_as_int(x), 0x143, 0xc, 0xf, true); // row_bcast:31 rows2,3
    x += __int_as_float(v);
    return x;
}

// ---------------------------------------------------------------------------
// K0: zero s + w + ctx (contiguous tail after hbuf)
// ---------------------------------------------------------------------------
__global__ __launch_bounds__(256) void zero_kernel(float4* __restrict__ p, int n4)
{
    const int i = blockIdx.x * 256 + threadIdx.x;
    if (i < n4) p[i] = make_float4(0.f, 0.f, 0.f, 0.f);
}

// ---------------------------------------------------------------------------
// K1: scan + DPP-fused attention-score dot. grid (B,2), block 512 (thread=h).
// Explicit 2-stage pipeline: compute group k with register set A while tab
// reads for k+1 land in set B (vp fetched 2 groups ahead).
// ---------------------------------------------------------------------------
__global__ __launch_bounds__(512) void qrnn_scan5(
    const float* __restrict__ x,    // (B,T,3)
    const float* __restrict__ emb,  // (V,10)
    const float* __restrict__ Wf, const float* __restrict__ bf_,
    const float* __restrict__ Wb, const float* __restrict__ bb_,
    const float* __restrict__ Mu,   // (DH,1)
    __hip_bfloat16* __restrict__ hbuf,  // (B,T,DH)
    float* __restrict__ s)          // (B,T) pre-zeroed
{
    const int b = blockIdx.x, dir = blockIdx.y, h = threadIdx.x;
    const int lane63 = ((h & 63) == 63);
    const float* __restrict__ W    = dir ? Wb  : Wf;
    const float* __restrict__ bias = dir ? bb_ : bf_;

    extern __shared__ char smem[];
    float4*        tab = (float4*)smem;                       // [V][H]
    float2*        tsA = (float2*)(smem + TAB_BYTES);         // [T]
    unsigned char* vpk = (unsigned char*)(smem + TAB_BYTES + TSA_BYTES); // [T]

    {   // stage x: one thread per t
        const int t = h;
        const float* xp = x + ((size_t)b*T_ + t)*3;
        tsA[t] = make_float2(xp[0], xp[1]);
        vpk[t] = (unsigned char)(int)xp[2];
    }

    float w0[3], w1[3], wt[10][3];
#pragma unroll
    for (int g = 0; g < 3; ++g) {
        w0[g] = W[g*H_ + h];
        w1[g] = W[1536 + g*H_ + h];
#pragma unroll
        for (int e = 0; e < 10; ++e)
            wt[e][g] = W[(2+e)*1536 + g*H_ + h];
    }
    const float bz = bias[h], bfv = bias[H_+h], bov = bias[2*H_+h];

    const float FZ = -2.8853900817779268f;   // -2*log2(e)
    const float FF = -1.4426950408889634f;   // -log2(e)

#pragma unroll
    for (int v = 0; v < V_; ++v) {
        float a0 = bz, a1 = bfv, a2 = bov;
#pragma unroll
        for (int e = 0; e < 10; ++e) {
            const float ev = emb[v*10 + e];
            a0 = fmaf(ev, wt[e][0], a0);
            a1 = fmaf(ev, wt[e][1], a1);
            a2 = fmaf(ev, wt[e][2], a2);
        }
        tab[v*H_ + h] = make_float4(FZ*a0, FF*a1, FF*a2, 0.f);
    }
    const float w0z = FZ*w0[0], w0f = FF*w0[1], w0o = FF*w0[2];
    const float w1z = FZ*w1[0], w1f = FF*w1[1], w1o = FF*w1[2];
    const float mu = Mu[dir*H_ + h];
    __syncthreads();

    const float4* tsA4 = (const float4*)tsA;   // 2 steps per float4
    const uint2*  vp2  = (const uint2*)vpk;    // 8 steps per uint2

    float c = 0.f;
    __hip_bfloat16* hb = hbuf + (size_t)b*T_*DH_ + dir*H_ + h;
    float* sb = s + b*T_;

#define GIDX(i) (dir ? (63 - (i)) : (i))

#define SS(i, A0, A1, G, RED) { \
    const float zp = fmaf(A0, w0z, fmaf(A1, w1z, (G).x)); \
    const float fp = fmaf(A0, w0f, fmaf(A1, w1f, (G).y)); \
    const float op = fmaf(A0, w0o, fmaf(A1, w1o, (G).z)); \
    const float rz = __builtin_amdgcn_rcpf(1.f + __builtin_amdgcn_exp2f(zp)); \
    const float f  = __builtin_amdgcn_rcpf(1.f + __builtin_amdgcn_exp2f(fp)); \
    const float o  = __builtin_amdgcn_rcpf(1.f + __builtin_amdgcn_exp2f(op)); \
    const float z  = fmaf(2.f, rz, -1.f); \
    c = fmaf(f, c - z, z); \
    const float hv = fmaxf(o * c, 0.f); \
    hb[(size_t)(t0 + (i))*DH_] = __float2bfloat16(hv); \
    RED = wave_sum_dpp(hv * mu); \
}

#define COMPUTE(K, T0_,T1_,T2_,T3_, G0,G1,G2,G3,G4,G5,G6,G7) { \
    const int t0 = (K)*8; \
    float r0,r1,r2,r3,r4,r5,r6,r7; \
    if (dir == 0) { \
        SS(0,T0_.x,T0_.y,G0,r0) SS(1,T0_.z,T0_.w,G1,r1) \
        SS(2,T1_.x,T1_.y,G2,r2) SS(3,T1_.z,T1_.w,G3,r3) \
        SS(4,T2_.x,T2_.y,G4,r4) SS(5,T2_.z,T2_.w,G5,r5) \
        SS(6,T3_.x,T3_.y,G6,r6) SS(7,T3_.z,T3_.w,G7,r7) \
    } else { \
        SS(7,T3_.z,T3_.w,G7,r7) SS(6,T3_.x,T3_.y,G6,r6) \
        SS(5,T2_.z,T2_.w,G5,r5) SS(4,T2_.x,T2_.y,G4,r4) \
        SS(3,T1_.z,T1_.w,G3,r3) SS(2,T1_.x,T1_.y,G2,r2) \
        SS(1,T0_.z,T0_.w,G1,r1) SS(0,T0_.x,T0_.y,G0,r0) \
    } \
    if (lane63) { \
        atomicAdd(&sb[t0+0], r0); atomicAdd(&sb[t0+1], r1); \
        atomicAdd(&sb[t0+2], r2); atomicAdd(&sb[t0+3], r3); \
        atomicAdd(&sb[t0+4], r4); atomicAdd(&sb[t0+5], r5); \
        atomicAdd(&sb[t0+6], r6); atomicAdd(&sb[t0+7], r7); \
    } \
}

#define TABRD(D0,D1,D2,D3,D4,D5,D6,D7, VP) \
    D0 = tab[(( (VP).x       ) & 255)*H_ + h]; \
    D1 = tab[(( (VP).x >>  8 ) & 255)*H_ + h]; \
    D2 = tab[(( (VP).x >> 16 ) & 255)*H_ + h]; \
    D3 = tab[(( (VP).x >> 24 )      )*H_ + h]; \
    D4 = tab[(( (VP).y       ) & 255)*H_ + h]; \
    D5 = tab[(( (VP).y >>  8 ) & 255)*H_ + h]; \
    D6 = tab[(( (VP).y >> 16 ) & 255)*H_ + h]; \
    D7 = tab[(( (VP).y >> 24 )      )*H_ + h];

    // ---- prologue: group0 tab -> A set; vp of group1 -> vpY; ts of group0 ----
    const int k0 = GIDX(0), k1 = GIDX(1);
    uint2 vpP = vp2[k0];
    float4 tsE0 = tsA4[k0*4+0], tsE1 = tsA4[k0*4+1];
    float4 tsE2 = tsA4[k0*4+2], tsE3 = tsA4[k0*4+3];
    uint2 vpY = vp2[k1];
    float4 gA0,gA1,gA2,gA3,gA4,gA5,gA6,gA7;
    float4 gB0,gB1,gB2,gB3,gB4,gB5,gB6,gB7;
    float4 tsO0, tsO1, tsO2, tsO3;
    uint2 vpX;
    TABRD(gA0,gA1,gA2,gA3,gA4,gA5,gA6,gA7, vpP)

    for (int gi = 0; gi < 64; gi += 2) {
        // EVEN: compute gi with (tsE, gA); prefetch gi+1 tab->gB (from vpY),
        //       ts(gi+1)->tsO, vp(gi+2)->vpX
        {
            const int iN1 = GIDX(gi+1);
            const int iN2 = GIDX(gi+2 <= 63 ? gi+2 : 63);
            vpX  = vp2[iN2];
            tsO0 = tsA4[iN1*4+0]; tsO1 = tsA4[iN1*4+1];
            tsO2 = tsA4[iN1*4+2]; tsO3 = tsA4[iN1*4+3];
            TABRD(gB0,gB1,gB2,gB3,gB4,gB5,gB6,gB7, vpY)
            COMPUTE(GIDX(gi), tsE0,tsE1,tsE2,tsE3, gA0,gA1,gA2,gA3,gA4,gA5,gA6,gA7)
        }
        // ODD: compute gi+1 with (tsO, gB); prefetch gi+2 tab->gA (from vpX),
        //      ts(gi+2)->tsE, vp(gi+3)->vpY
        {
            const int iN2 = GIDX(gi+2 <= 63 ? gi+2 : 63);
            const int iN3 = GIDX(gi+3 <= 63 ? gi+3 : 63);
            vpY  = vp2[iN3];
            tsE0 = tsA4[iN2*4+0]; tsE1 = tsA4[iN2*4+1];
            tsE2 = tsA4[iN2*4+2]; tsE3 = tsA4[iN2*4+3];
            TABRD(gA0,gA1,gA2,gA3,gA4,gA5,gA6,gA7, vpX)
            COMPUTE(GIDX(gi+1), tsO0,tsO1,tsO2,tsO3, gB0,gB1,gB2,gB3,gB4,gB5,gB6,gB7)
        }
    }
#undef TABRD
#undef COMPUTE
#undef SS
#undef GIDX
}

// ---------------------------------------------------------------------------
// K3: softmax over t per batch. grid B, block 512.
// ---------------------------------------------------------------------------
__global__ __launch_bounds__(512) void softmax_kernel(
    const float* __restrict__ s, float* __restrict__ w)
{
    const int b = blockIdx.x;
    const int t = threadIdx.x;
    const float v = s[b*T_ + t];

    __shared__ float redm[8];
    __shared__ float reds[8];

    float m = v;
#pragma unroll
    for (int off = 32; off; off >>= 1) m = fmaxf(m, __shfl_xor(m, off));
    if ((t & 63) == 0) redm[t >> 6] = m;
    __syncthreads();
    float mall = redm[0];
#pragma unroll
    for (int i = 1; i < 8; ++i) mall = fmaxf(mall, redm[i]);

    const float e = __expf(v - mall);
    float sum = e;
#pragma unroll
    for (int off = 32; off; off >>= 1) sum += __shfl_xor(sum, off);
    if ((t & 63) == 0) reds[t >> 6] = sum;
    __syncthreads();
    float sall = 0.f;
#pragma unroll
    for (int i = 0; i < 8; ++i) sall += reds[i];

    w[b*T_ + t] = e / sall;
}

// ---------------------------------------------------------------------------
// K4: context partial over a T-chunk; accumulate into zeroed ctx via atomics.
// grid (B,8), block 256; thread owns 4 d's.
// ---------------------------------------------------------------------------
__global__ __launch_bounds__(256) void context3(
    const __hip_bfloat16* __restrict__ hbuf, const float* __restrict__ w,
    float* __restrict__ ctx)
{
    const int b = blockIdx.x, q = blockIdx.y;
    const int d0 = threadIdx.x * 4;

    __shared__ float ws[64];
    if (threadIdx.x < 64) ws[threadIdx.x] = w[b*T_ + q*64 + threadIdx.x];
    __syncthreads();

    const char* hp = (const char*)(hbuf + ((size_t)b*T_ + q*64)*DH_ + d0);
    float a0 = 0.f, a1 = 0.f, a2 = 0.f, a3 = 0.f;
#pragma unroll 8
    for (int i = 0; i < 64; ++i) {
        const uint2 u = *(const uint2*)(hp + (size_t)i*(DH_*2));
        const float wv = ws[i];
        a0 = fmaf(bf2f((unsigned short)(u.x & 0xffffu)), wv, a0);
        a1 = fmaf(bf2f((unsigned short)(u.x >> 16)),     wv, a1);
        a2 = fmaf(bf2f((unsigned short)(u.y & 0xffffu)), wv, a2);
        a3 = fmaf(bf2f((unsigned short)(u.y >> 16)),     wv, a3);
    }
    float* cp = ctx + b*DH_ + d0;
    atomicAdd(cp + 0, a0);
    atomicAdd(cp + 1, a1);
    atomicAdd(cp + 2, a2);
    atomicAdd(cp + 3, a3);
}

// ---------------------------------------------------------------------------
// K5: out[b,o] = dot(relu(ctx[b,:]), W_out[o,:]) + b_out[o]. One wave per (b,o).
// ---------------------------------------------------------------------------
__global__ __launch_bounds__(256) void out_kernel(
    const float* __restrict__ ctx, const float* __restrict__ Wout,
    const float* __restrict__ bout, float* __restrict__ out)
{
    const int idx  = blockIdx.x*4 + (threadIdx.x >> 6);  // b*64 + o
    const int lane = threadIdx.x & 63;
    const int b = idx >> 6;
    const int o = idx & 63;
    const float* cp = ctx + b*DH_;
    const float* wp = Wout + o*DH_;
    float acc = 0.f;
#pragma unroll
    for (int k = 0; k < DH_/64; ++k) {
        const int d = lane + k*64;
        acc = fmaf(fmaxf(cp[d], 0.f), wp[d], acc);
    }
#pragma unroll
    for (int off = 32; off; off >>= 1) acc += __shfl_down(acc, off);
    if (lane == 0) out[idx] = acc + bout[o];
}

// ---------------------------------------------------------------------------
extern "C" void kernel_launch(void* const* d_in, const int* in_sizes, int n_in,
                              void* d_out, int out_size, void* d_ws, size_t ws_size,
                              hipStream_t stream)
{
    const float* x    = (const float*)d_in[0];
    const float* emb  = (const float*)d_in[1];
    const float* Wf   = (const float*)d_in[2];
    const float* bf_  = (const float*)d_in[3];
    const float* Wb   = (const float*)d_in[4];
    const float* bb_  = (const float*)d_in[5];
    const float* Mu   = (const float*)d_in[6];
    const float* Wout = (const float*)d_in[7];
    const float* bout = (const float*)d_in[8];
    float* out = (float*)d_out;

    char* ws = (char*)d_ws;
    const size_t hbytes = (size_t)B_*T_*DH_*sizeof(__hip_bfloat16);  // 134.2 MB
    __hip_bfloat16* hbuf = (__hip_bfloat16*)ws;
    float* s   = (float*)(ws + hbytes);   // B*T
    float* w   = s + B_*T_;               // B*T
    float* ctx = w + B_*T_;               // B*DH

    (void)hipFuncSetAttribute((const void*)qrnn_scan5,
                              hipFuncAttributeMaxDynamicSharedMemorySize,
                              SCAN_LDS);

    // zero s + w + ctx (contiguous): (2*B*T + B*DH)/4 float4s
    const int n4 = (2*B_*T_ + B_*DH_) / 4;
    zero_kernel<<<(n4 + 255)/256, 256, 0, stream>>>((float4*)s, n4);

    qrnn_scan5<<<dim3(B_, 2), 512, SCAN_LDS, stream>>>(x, emb, Wf, bf_, Wb, bb_,
                                                       Mu, hbuf, s);
    softmax_kernel<<<B_, 512, 0, stream>>>(s, w);
    context3<<<dim3(B_, 8), 256, 0, stream>>>(hbuf, w, ctx);
    out_kernel<<<(B_*OUT_)/4, 256, 0, stream>>>(ctx, Wout, bout, out);
}